// Round 11
// baseline (601.786 us; speedup 1.0000x reference)
//
#include <hip/hip_runtime.h>
#include <hip/hip_bf16.h>
#include <cstdint>

// Problem constants: B=1, C=256, F=8, H=32, W=32 -> N = 8192 spatial.
#define NSP 8192
#define CCH 256
#define KBLK 32
#define NSPLIT 8
#define KEYS_PER_SPLIT 1024
#define NTILES 32  // KEYS_PER_SPLIT / KBLK

typedef __attribute__((ext_vector_type(4))) float f32x4;
typedef __attribute__((ext_vector_type(16))) float f32x16;
typedef __attribute__((ext_vector_type(8))) short bf16x8;
typedef __attribute__((ext_vector_type(2))) unsigned int u32x2;

__device__ __forceinline__ ushort f2bf(float f) {
  union { float f; uint32_t u; } v; v.f = f;
  uint32_t r = (v.u + 0x7FFFu + ((v.u >> 16) & 1u)) >> 16;
  return (ushort)r;
}
__device__ __forceinline__ float bf2f(ushort u) {
  union { uint32_t u; float f; } v; v.u = ((uint32_t)u) << 16; return v.f;
}
__device__ __forceinline__ uint32_t pk2bf(float lo, float hi) {
  __hip_bfloat162 h = __float22bfloat162_rn({lo, hi});
  union { __hip_bfloat162 h; uint32_t u; } c; c.h = h; return c.u;
}

// global -> LDS direct copy, 16B per lane. LDS dest must be wave-uniform base.
__device__ __forceinline__ void gload_lds16(const void* g, void* l) {
  auto gp = (const __attribute__((address_space(1))) uint32_t*)(uintptr_t)g;
  auto lp = (__attribute__((address_space(3))) uint32_t*)(uint32_t)(uintptr_t)l;
  __builtin_amdgcn_global_load_lds(gp, lp, 16, 0, 0);
}

// exchange: swaps hi 32 lanes of a with lo 32 lanes of b
__device__ __forceinline__ void perm32swap(uint32_t& a, uint32_t& b) {
#if __has_builtin(__builtin_amdgcn_permlane32_swap)
  u32x2 r = __builtin_amdgcn_permlane32_swap(a, b, false, false);
  a = r[0]; b = r[1];
#else
  uint32_t sa = __shfl_xor((int)a, 32), sb = __shfl_xor((int)b, 32);
  bool lo = (threadIdx.x & 63) < 32;
  uint32_t na = lo ? a : sb;
  uint32_t nb = lo ? sa : b;
  a = na; b = nb;
#endif
}

// ---------------- K1: per-block partial sum/sumsq over x (2M floats) --------
__global__ __launch_bounds__(256) void k_stats1(const float* __restrict__ x,
                                                float* __restrict__ part) {
  int t = threadIdx.x, b = blockIdx.x;
  float s = 0.f, ss = 0.f;
  const float4* x4 = (const float4*)x;
  for (int i = 0; i < 4; ++i) {
    float4 v = x4[(size_t)i * 131072 + b * 256 + t];
    s += v.x + v.y + v.z + v.w;
    ss += v.x * v.x + v.y * v.y + v.z * v.z + v.w * v.w;
  }
  for (int m = 1; m < 64; m <<= 1) { s += __shfl_xor(s, m); ss += __shfl_xor(ss, m); }
  __shared__ float ls[4], lss[4];
  int w = t >> 6, lane = t & 63;
  if (lane == 0) { ls[w] = s; lss[w] = ss; }
  __syncthreads();
  if (t == 0) {
    part[b * 2 + 0] = ls[0] + ls[1] + ls[2] + ls[3];
    part[b * 2 + 1] = lss[0] + lss[1] + lss[2] + lss[3];
  }
}

// ---------------- K2: cast weights to bf16; block 1024 finalizes stats ------
__global__ __launch_bounds__(256) void k_castw(const float* __restrict__ qw, const float* __restrict__ kw,
                                               const float* __restrict__ vw, const float* __restrict__ ow,
                                               ushort* __restrict__ wqkv, ushort* __restrict__ wo,
                                               const float* __restrict__ part, float* __restrict__ stat) {
  if (blockIdx.x == 1024) {  // stats finalize
    int t = threadIdx.x;
    float s = 0.f, ss = 0.f;
    for (int i = t; i < 512; i += 256) { s += part[i * 2]; ss += part[i * 2 + 1]; }
    for (int m = 1; m < 64; m <<= 1) { s += __shfl_xor(s, m); ss += __shfl_xor(ss, m); }
    __shared__ float ls[4], lss[4];
    int w = t >> 6, lane = t & 63;
    if (lane == 0) { ls[w] = s; lss[w] = ss; }
    __syncthreads();
    if (t == 0) {
      float sum = ls[0] + ls[1] + ls[2] + ls[3];
      float ssum = lss[0] + lss[1] + lss[2] + lss[3];
      float mean = sum * (1.f / 2097152.f);
      float var = ssum * (1.f / 2097152.f) - mean * mean;
      stat[0] = mean;
      stat[1] = rsqrtf(var + 1e-5f);
    }
    return;
  }
  int idx = blockIdx.x * 256 + threadIdx.x;  // 262144 total
  if (idx < 65536) wqkv[idx] = f2bf(qw[idx]);
  else if (idx < 131072) wqkv[idx] = f2bf(kw[idx - 65536]);
  else if (idx < 196608) wqkv[idx] = f2bf(vw[idx - 131072]);
  else wo[idx - 196608] = f2bf(ow[idx - 196608]);
}

// ---------------- K3: normalize + transpose -> xnT bf16 [8192][256] ---------
__global__ __launch_bounds__(256) void k_norm_t(const float* __restrict__ x,
                                                const float* __restrict__ gw, const float* __restrict__ gb,
                                                const float* __restrict__ stat, ushort* __restrict__ xnT) {
  __shared__ float tile[64][66];
  int n0 = blockIdx.x * 64, c0 = blockIdx.y * 64;
  int t = threadIdx.x, colr = t & 63, rq = t >> 6;
  float mean = stat[0], rinv = stat[1];
  for (int rr = 0; rr < 16; ++rr) {
    int row = rr * 4 + rq;  // c-local
    int c = c0 + row;
    float v = x[(size_t)c * NSP + n0 + colr];
    tile[row][colr] = (v - mean) * rinv * gw[c] + gb[c];
  }
  __syncthreads();
  for (int rr = 0; rr < 16; ++rr) {
    int rowW = rr * 4 + rq;  // n-local
    xnT[(size_t)(n0 + rowW) * 256 + c0 + colr] = f2bf(tile[colr][rowW]);
  }
}

// ---------------- K4: QKV GEMM -> qT(scaled)/kT [8192][256],
//                  V packed per key-tile: v_tiles[256 tile][4 slot][256 c][8 m]
__global__ __launch_bounds__(256) void k_qkv(const ushort* __restrict__ xnT, const ushort* __restrict__ wqkv,
                                             const float* __restrict__ qb, const float* __restrict__ kb,
                                             const float* __restrict__ vb,
                                             ushort* __restrict__ qT, ushort* __restrict__ kT,
                                             ushort* __restrict__ v_tiles) {
  __shared__ ushort tile[64][80];  // V transpose bounce (160B rows, 16B aligned)
  int nb = blockIdx.x, ob = blockIdx.y;
  int w = threadIdx.x >> 6, lane = threadIdx.x & 63;
  int l16 = lane & 15, kgrp = lane >> 4;
  int n_row = nb * 64 + w * 16 + l16;
  bf16x8 a[8];
  const bf16x8* arow = (const bf16x8*)(xnT + (size_t)n_row * 256);
  for (int ks = 0; ks < 8; ++ks) a[ks] = arow[ks * 4 + kgrp];
  f32x4 acc[4];
  for (int ct = 0; ct < 4; ++ct) {
    int o = ob * 64 + ct * 16 + l16;
    const bf16x8* brow = (const bf16x8*)(wqkv + (size_t)o * 256);
    f32x4 c = {0.f, 0.f, 0.f, 0.f};
    for (int ks = 0; ks < 8; ++ks)
      c = __builtin_amdgcn_mfma_f32_16x16x32_bf16(a[ks], brow[ks * 4 + kgrp], c, 0, 0, 0);
    acc[ct] = c;
  }
  const float SCALE = 0.0625f * 1.44269504088896340736f;  // (1/sqrt(C)) * log2(e)
  if (ob < 8) {  // q / k outputs
    for (int ct = 0; ct < 4; ++ct) {
      int o = ob * 64 + ct * 16 + l16;
      for (int r = 0; r < 4; ++r) {
        int n = nb * 64 + w * 16 + kgrp * 4 + r;
        float v = acc[ct][r];
        if (o < 256) qT[(size_t)n * 256 + o] = f2bf((v + qb[o]) * SCALE);
        else kT[(size_t)n * 256 + (o - 256)] = f2bf(v + kb[o - 256]);
      }
    }
  } else {  // v outputs: bounce via LDS, emit tile-packed layout, coalesced
    for (int ct = 0; ct < 4; ++ct) {
      int o_l = ct * 16 + l16;
      for (int r = 0; r < 4; ++r) {
        int n_l = w * 16 + kgrp * 4 + r;
        tile[o_l][n_l] = f2bf(acc[ct][r] + vb[(ob - 8) * 64 + o_l]);
      }
    }
    __syncthreads();
    // v_tiles element (t, s, c, m) at ushort offset t*8192 + s*2048 + c*8 + m
    for (int j = 0; j < 2; ++j) {
      int idx = j * 256 + threadIdx.x;          // 512 stores of 16B
      int tile_l = idx >> 8, slot = (idx >> 6) & 3, c_l = idx & 63;
      size_t off = (size_t)(nb * 2 + tile_l) * 8192 + slot * 2048 +
                   (size_t)((ob - 8) * 64 + c_l) * 8;
      *(uint4*)((char*)v_tiles + off * 2) = *(const uint4*)&tile[c_l][tile_l * 32 + slot * 8];
    }
  }
}

// ---------------- K5: flash attention, 64 q/wave, cross-tile pipelined ------
// grid 256 = 1 block/CU (32 qblk x 8 splits, split = bid&7 -> XCD-exact).
// 256 threads (4 waves) at 1 wave/SIMD (launch_bounds(256,1) -> 512-reg budget).
// Wave owns 64 q = TWO 32-q groups: each K/V ds_read feeds BOTH groups' MFMAs
// -> per-CU LDS traffic halves vs r10 (4 waves x 32KB = 128KB/tile).
// Regs: acc 2x8 f32x16 = 256 AGPR + qf 128 + S 32 + pf 16 + temps ~= 460.
// Pipeline (r10): iter tt = PV(tt-1) interleaved with QK^T(tt), then softmax.
__global__ __launch_bounds__(256, 1) void k_attn(const ushort* __restrict__ qT, const ushort* __restrict__ kT,
                                                 const ushort* __restrict__ v_tiles,
                                                 ushort* __restrict__ Opart, float* __restrict__ mpart,
                                                 float* __restrict__ lpart) {
  __shared__ __align__(16) ushort SMEM[32768];  // 64 KB
  ushort* k_lds = SMEM;          // 2 x 8192: [32 key][256 c], 16B slots XOR-swz by key&7
  ushort* v_lds = SMEM + 16384;  // 2 x 8192: [slot s<4][256 c][8 m] (linear tile image)

  int bid = blockIdx.x;
  int split = bid & 7, qblk = bid >> 3;
  int t = threadIdx.x, w = t >> 6, lane = t & 63;
  int l31 = lane & 31, lhi = lane >> 5, l7 = lane & 7;
  int q0w = qblk * 256 + w * 64;

  // Q fragments for both 32-q groups: lane holds q = q0w + g*32 + l31
  bf16x8 qf0[16], qf1[16];
  {
    const char* qb0 = (const char*)qT + (size_t)(q0w + l31) * 512;
    const char* qb1 = (const char*)qT + (size_t)(q0w + 32 + l31) * 512;
#pragma unroll
    for (int cs = 0; cs < 16; ++cs) {
      qf0[cs] = *(const bf16x8*)(qb0 + cs * 32 + lhi * 16);
      qf1[cs] = *(const bf16x8*)(qb1 + cs * 32 + lhi * 16);
    }
  }

  f32x16 acc0[8] = {}, acc1[8] = {};   // O[c][q] per group (AGPRs)
  float m0 = -1e30f, l0 = 0.f, m1 = -1e30f, l1 = 0.f;
  bf16x8 pfA0, pfA1, pfB0, pfB1;       // P fragments of previous tile (2 groups)

  const char* kT_b = (const char*)kT + (size_t)split * KEYS_PER_SPLIT * 512;
  const char* v_b = (const char*)v_tiles + (size_t)split * KEYS_PER_SPLIT * 512;

  // stage K(tt)/V(tt) -> buf[tt&1]; 4+4 gload_lds per wave (4 waves)
  auto STAGE_K = [&](int tt) {
    const char* ksrc = kT_b + (size_t)tt * KBLK * 512;
    char* kdst = (char*)(k_lds + (tt & 1) * 8192) + w * 4096;
#pragma unroll
    for (int i = 0; i < 4; ++i) {
      int keyloc = w * 8 + i * 2 + lhi;
      int srcoff = keyloc * 512 + ((l31 ^ (keyloc & 7)) << 4);
      gload_lds16(ksrc + srcoff, kdst + i * 1024);
    }
  };
  auto STAGE_V = [&](int tt) {
    char* vdst = (char*)(v_lds + (tt & 1) * 8192) + w * 4096;
    const char* vsrc = v_b + (size_t)tt * 16384 + w * 4096;
#pragma unroll
    for (int i = 0; i < 4; ++i)
      gload_lds16(vsrc + i * 1024 + lane * 16, vdst + i * 1024);
  };

  // softmax both groups + pack P fragments (defer-max fast path)
  auto SOFTMAX2 = [&](f32x16& S0, f32x16& S1) {
    float pa = fmaxf(fmaxf(fmaxf(fmaxf(S0[0], S0[1]), fmaxf(S0[2], S0[3])),
                           fmaxf(fmaxf(S0[4], S0[5]), fmaxf(S0[6], S0[7]))),
                     fmaxf(fmaxf(fmaxf(S0[8], S0[9]), fmaxf(S0[10], S0[11])),
                           fmaxf(fmaxf(S0[12], S0[13]), fmaxf(S0[14], S0[15]))));
    float pb = fmaxf(fmaxf(fmaxf(fmaxf(S1[0], S1[1]), fmaxf(S1[2], S1[3])),
                           fmaxf(fmaxf(S1[4], S1[5]), fmaxf(S1[6], S1[7]))),
                     fmaxf(fmaxf(fmaxf(S1[8], S1[9]), fmaxf(S1[10], S1[11])),
                           fmaxf(fmaxf(S1[12], S1[13]), fmaxf(S1[14], S1[15]))));
    pa = fmaxf(pa, __shfl_xor(pa, 32));
    pb = fmaxf(pb, __shfl_xor(pb, 32));
    bool ok = (pa <= m0 + 8.f) && (pb <= m1 + 8.f);
    if (!__all(ok)) {   // slow path (rare)
      float mn0 = fmaxf(m0, pa), a0 = __builtin_amdgcn_exp2f(m0 - mn0);
      float mn1 = fmaxf(m1, pb), a1 = __builtin_amdgcn_exp2f(m1 - mn1);
      m0 = mn0; l0 *= a0; m1 = mn1; l1 *= a1;
#pragma unroll
      for (int cb = 0; cb < 8; ++cb)
#pragma unroll
        for (int r = 0; r < 16; ++r) { acc0[cb][r] *= a0; acc1[cb][r] *= a1; }
    }
    {
      float s0 = 0.f, s1 = 0.f, s2 = 0.f, s3 = 0.f;
#pragma unroll
      for (int r = 0; r < 16; ++r) {
        S0[r] = __builtin_amdgcn_exp2f(S0[r] - m0);
        S1[r] = __builtin_amdgcn_exp2f(S1[r] - m1);
        if (r < 8) { s0 += S0[r]; s1 += S1[r]; }
        else { s2 += S0[r]; s3 += S1[r]; }
      }
      l0 += s0 + s2; l1 += s1 + s3;
    }
    union { uint32_t w[4]; bf16x8 v; } u;
    {
      uint32_t x = pk2bf(S0[0], S0[1]), y = pk2bf(S0[4], S0[5]);
      perm32swap(x, y);
      uint32_t x2_ = pk2bf(S0[2], S0[3]), y2 = pk2bf(S0[6], S0[7]);
      perm32swap(x2_, y2);
      u.w[0] = x; u.w[1] = x2_; u.w[2] = y; u.w[3] = y2; pfA0 = u.v;
    }
    {
      uint32_t x = pk2bf(S0[8], S0[9]), y = pk2bf(S0[12], S0[13]);
      perm32swap(x, y);
      uint32_t x2_ = pk2bf(S0[10], S0[11]), y2 = pk2bf(S0[14], S0[15]);
      perm32swap(x2_, y2);
      u.w[0] = x; u.w[1] = x2_; u.w[2] = y; u.w[3] = y2; pfA1 = u.v;
    }
    {
      uint32_t x = pk2bf(S1[0], S1[1]), y = pk2bf(S1[4], S1[5]);
      perm32swap(x, y);
      uint32_t x2_ = pk2bf(S1[2], S1[3]), y2 = pk2bf(S1[6], S1[7]);
      perm32swap(x2_, y2);
      u.w[0] = x; u.w[1] = x2_; u.w[2] = y; u.w[3] = y2; pfB0 = u.v;
    }
    {
      uint32_t x = pk2bf(S1[8], S1[9]), y = pk2bf(S1[12], S1[13]);
      perm32swap(x, y);
      uint32_t x2_ = pk2bf(S1[10], S1[11]), y2 = pk2bf(S1[14], S1[15]);
      perm32swap(x2_, y2);
      u.w[0] = x; u.w[1] = x2_; u.w[2] = y; u.w[3] = y2; pfB1 = u.v;
    }
  };

  STAGE_K(0);  // prologue

  // ---- iter 0 (peeled): QK^T(0) both groups ----
  asm volatile("s_waitcnt vmcnt(0) lgkmcnt(0)" ::: "memory");
  __builtin_amdgcn_s_barrier();
  __builtin_amdgcn_sched_barrier(0);
  STAGE_K(1);
  STAGE_V(0);
  {
    const ushort* kl = k_lds;  // buf 0
    f32x16 S0 = {}, S1 = {};
    __builtin_amdgcn_s_setprio(1);
#pragma unroll
    for (int cs = 0; cs < 16; ++cs) {
      int slot = (cs * 2 + lhi) ^ l7;
      bf16x8 ka = *(const bf16x8*)(kl + l31 * 256 + slot * 8);
      S0 = __builtin_amdgcn_mfma_f32_32x32x16_bf16(ka, qf0[cs], S0, 0, 0, 0);
      S1 = __builtin_amdgcn_mfma_f32_32x32x16_bf16(ka, qf1[cs], S1, 0, 0, 0);
    }
    __builtin_amdgcn_s_setprio(0);
    SOFTMAX2(S0, S1);
  }

#pragma unroll 1
  for (int tt = 1; tt < NTILES; ++tt) {
    asm volatile("s_waitcnt vmcnt(0) lgkmcnt(0)" ::: "memory");
    __builtin_amdgcn_s_barrier();
    __builtin_amdgcn_sched_barrier(0);
    if (tt + 1 < NTILES) STAGE_K(tt + 1);
    STAGE_V(tt);

    // ---- interleaved cluster: PV(tt-1) + QK^T(tt), both groups ----
    const ushort* kl = k_lds + (tt & 1) * 8192;
    const ushort* vl = v_lds + ((tt - 1) & 1) * 8192;
    f32x16 S0 = {}, S1 = {};
    __builtin_amdgcn_s_setprio(1);
#pragma unroll
    for (int cb = 0; cb < 8; ++cb) {
      bf16x8 va0 = *(const bf16x8*)(vl + (0 + lhi) * 2048 + (cb * 32 + l31) * 8);
      acc0[cb] = __builtin_amdgcn_mfma_f32_32x32x16_bf16(va0, pfA0, acc0[cb], 0, 0, 0);
      acc1[cb] = __builtin_amdgcn_mfma_f32_32x32x16_bf16(va0, pfB0, acc1[cb], 0, 0, 0);
      {
        int cs = 2 * cb;
        int slot = (cs * 2 + lhi) ^ l7;
        bf16x8 ka = *(const bf16x8*)(kl + l31 * 256 + slot * 8);
        S0 = __builtin_amdgcn_mfma_f32_32x32x16_bf16(ka, qf0[cs], S0, 0, 0, 0);
        S1 = __builtin_amdgcn_mfma_f32_32x32x16_bf16(ka, qf1[cs], S1, 0, 0, 0);
      }
      bf16x8 va1 = *(const bf16x8*)(vl + (2 + lhi) * 2048 + (cb * 32 + l31) * 8);
      acc0[cb] = __builtin_amdgcn_mfma_f32_32x32x16_bf16(va1, pfA1, acc0[cb], 0, 0, 0);
      acc1[cb] = __builtin_amdgcn_mfma_f32_32x32x16_bf16(va1, pfB1, acc1[cb], 0, 0, 0);
      {
        int cs = 2 * cb + 1;
        int slot = (cs * 2 + lhi) ^ l7;
        bf16x8 ka = *(const bf16x8*)(kl + l31 * 256 + slot * 8);
        S0 = __builtin_amdgcn_mfma_f32_32x32x16_bf16(ka, qf0[cs], S0, 0, 0, 0);
        S1 = __builtin_amdgcn_mfma_f32_32x32x16_bf16(ka, qf1[cs], S1, 0, 0, 0);
      }
    }
    __builtin_amdgcn_s_setprio(0);
    SOFTMAX2(S0, S1);
  }

  // ---- drain: PV(NTILES-1), both groups ----
  asm volatile("s_waitcnt vmcnt(0) lgkmcnt(0)" ::: "memory");
  __builtin_amdgcn_s_barrier();
  {
    const ushort* vl = v_lds + ((NTILES - 1) & 1) * 8192;
    __builtin_amdgcn_s_setprio(1);
#pragma unroll
    for (int cb = 0; cb < 8; ++cb) {
      bf16x8 va0 = *(const bf16x8*)(vl + (0 + lhi) * 2048 + (cb * 32 + l31) * 8);
      acc0[cb] = __builtin_amdgcn_mfma_f32_32x32x16_bf16(va0, pfA0, acc0[cb], 0, 0, 0);
      acc1[cb] = __builtin_amdgcn_mfma_f32_32x32x16_bf16(va0, pfB0, acc1[cb], 0, 0, 0);
      bf16x8 va1 = *(const bf16x8*)(vl + (2 + lhi) * 2048 + (cb * 32 + l31) * 8);
      acc0[cb] = __builtin_amdgcn_mfma_f32_32x32x16_bf16(va1, pfA1, acc0[cb], 0, 0, 0);
      acc1[cb] = __builtin_amdgcn_mfma_f32_32x32x16_bf16(va1, pfB1, acc1[cb], 0, 0, 0);
    }
    __builtin_amdgcn_s_setprio(0);
  }

  // all waves done with LDS before reusing it as epilogue scratch
  asm volatile("s_waitcnt lgkmcnt(0)" ::: "memory");
  __builtin_amdgcn_s_barrier();

  // ---- epilogue per group: O -> LDS transpose (64-c chunks) -> coalesced ----
  char* eb = (char*)SMEM + w * 4608;  // 32 q-rows x 144B per wave
#pragma unroll
  for (int g = 0; g < 2; ++g) {
    float lp = g ? l1 : l0;
    float mr = g ? m1 : m0;
    float l_tot = lp + __shfl_xor(lp, 32);
    size_t gq0 = (size_t)split * NSP + q0w + g * 32;
#pragma unroll
    for (int ch = 0; ch < 4; ++ch) {
#pragma unroll
      for (int cb2 = 0; cb2 < 2; ++cb2) {
        int cb = ch * 2 + cb2;
        f32x16 av = g ? acc1[cb] : acc0[cb];
#pragma unroll
        for (int gs = 0; gs < 4; ++gs) {
          int cl = cb2 * 32 + gs * 8 + 4 * lhi;
          *(uint32_t*)(eb + l31 * 144 + cl * 2) = pk2bf(av[gs * 4 + 0], av[gs * 4 + 1]);
          *(uint32_t*)(eb + l31 * 144 + cl * 2 + 4) = pk2bf(av[gs * 4 + 2], av[gs * 4 + 3]);
        }
      }
      asm volatile("s_waitcnt lgkmcnt(0)" ::: "memory");
      __builtin_amdgcn_sched_barrier(0);
#pragma unroll
      for (int i = 0; i < 4; ++i) {
        int flat = i * 1024 + lane * 16;
        int qr = flat >> 7, off = flat & 127;
        uint4 val = *(const uint4*)(eb + qr * 144 + off);
        *(uint4*)((char*)Opart + (gq0 + qr) * 512 + ch * 128 + off) = val;
      }
      asm volatile("s_waitcnt lgkmcnt(0)" ::: "memory");
      __builtin_amdgcn_sched_barrier(0);
    }
    if (lane < 32) {
      int q = q0w + g * 32 + l31;
      mpart[split * NSP + q] = mr;
      lpart[split * NSP + q] = l_tot;
    }
  }
}

// ---------------- K6: combine split partials -> attT bf16 [8192][256] -------
// 8 q-rows per block; each thread handles 8 channels via bf16x8 (vectorized).
__global__ __launch_bounds__(256) void k_combine(const ushort* __restrict__ Opart,
                                                 const float* __restrict__ mpart,
                                                 const float* __restrict__ lpart,
                                                 ushort* __restrict__ attT) {
  int q = blockIdx.x * 8 + (threadIdx.x >> 5);
  int c8 = threadIdx.x & 31;  // channels c8*8 .. c8*8+7
  float M = -1e30f;
#pragma unroll
  for (int s = 0; s < NSPLIT; ++s) M = fmaxf(M, mpart[s * NSP + q]);
  float L = 0.f;
  float av[8] = {};
#pragma unroll
  for (int s = 0; s < NSPLIT; ++s) {
    float ws = __builtin_amdgcn_exp2f(mpart[s * NSP + q] - M);
    L += ws * lpart[s * NSP + q];
    bf16x8 o = *(const bf16x8*)(Opart + ((size_t)s * NSP + q) * 256 + c8 * 8);
#pragma unroll
    for (int j = 0; j < 8; ++j) av[j] += ws * bf2f((ushort)o[j]);
  }
  float rL = 1.f / L;
  uint4 outv;
  outv.x = pk2bf(av[0] * rL, av[1] * rL);
  outv.y = pk2bf(av[2] * rL, av[3] * rL);
  outv.z = pk2bf(av[4] * rL, av[5] * rL);
  outv.w = pk2bf(av[6] * rL, av[7] * rL);
  *(uint4*)(attT + (size_t)q * 256 + c8 * 8) = outv;
}

// ---------------- K7: out = xn + ow @ att + ob ------------------------------
__global__ __launch_bounds__(256) void k_final(const ushort* __restrict__ attT, const ushort* __restrict__ wo,
                                               const float* __restrict__ ob, const float* __restrict__ x,
                                               const float* __restrict__ gw, const float* __restrict__ gb,
                                               const float* __restrict__ stat, float* __restrict__ out) {
  int nb = blockIdx.x, obk = blockIdx.y;
  int w = threadIdx.x >> 6, lane = threadIdx.x & 63;
  int l16 = lane & 15, kgrp = lane >> 4;
  int orow = obk * 64 + w * 16 + l16;
  bf16x8 a[8];
  const bf16x8* arow = (const bf16x8*)(wo + (size_t)orow * 256);
  for (int ks = 0; ks < 8; ++ks) a[ks] = arow[ks * 4 + kgrp];
  float mean = stat[0], rinv = stat[1];
  f32x4 acc[4];
  for (int ct = 0; ct < 4; ++ct) {
    int n = nb * 64 + ct * 16 + l16;
    const bf16x8* brow = (const bf16x8*)(attT + (size_t)n * 256);
    f32x4 c = {0.f, 0.f, 0.f, 0.f};
    for (int ks = 0; ks < 8; ++ks)
      c = __builtin_amdgcn_mfma_f32_16x16x32_bf16(a[ks], brow[ks * 4 + kgrp], c, 0, 0, 0);
    acc[ct] = c;
  }
  for (int ct = 0; ct < 4; ++ct) {
    for (int r = 0; r < 4; ++r) {
      int o = obk * 64 + w * 16 + kgrp * 4 + r;
      int n = nb * 64 + ct * 16 + l16;
      float xv = x[(size_t)o * NSP + n];
      float xn = (xv - mean) * rinv * gw[o] + gb[o];
      out[(size_t)o * NSP + n] = xn + acc[ct][r] + ob[o];
    }
  }
}

extern "C" void kernel_launch(void* const* d_in, const int* in_sizes, int n_in,
                              void* d_out, int out_size, void* d_ws, size_t ws_size,
                              hipStream_t stream) {
  const float* x = (const float*)d_in[0];
  const float* gw = (const float*)d_in[1];
  const float* gb = (const float*)d_in[2];
  const float* qw = (const float*)d_in[3];
  const float* qbv = (const float*)d_in[4];
  const float* kw = (const float*)d_in[5];
  const float* kbv = (const float*)d_in[6];
  const float* vw = (const float*)d_in[7];
  const float* vbv = (const float*)d_in[8];
  const float* ow = (const float*)d_in[9];
  const float* obv = (const float*)d_in[10];
  float* out = (float*)d_out;
  char* ws = (char*)d_ws;
  const size_t KB = 1024, MB = 1048576;
  // region plan (high-water 49 MB):
  //  0..4K      part
  //  60K        stat
  //  64..448K   wqkv (dead after k_qkv) -> mpart (256K) overlays
  //  448..576K  wo (live until k_final)
  //  576..832K  lpart
  //  1..5MB     xnT (k_norm_t->k_qkv) -> attT (k_combine->k_final)
  //  5..9MB     qT
  //  9..13MB    kT
  //  13..17MB   v_tiles [256 tile][16KB]
  //  17..49MB   Opart (8 splits, bf16)
  float* part = (float*)(ws);
  float* stat = (float*)(ws + 60 * KB);
  ushort* wqkv = (ushort*)(ws + 64 * KB);
  ushort* wo = (ushort*)(ws + 448 * KB);
  float* mpart = (float*)(ws + 64 * KB);    // overlays wqkv (dead by k_attn)
  float* lpart = (float*)(ws + 576 * KB);
  ushort* xnT = (ushort*)(ws + 1 * MB);
  ushort* qT = (ushort*)(ws + 5 * MB);
  ushort* kT = (ushort*)(ws + 9 * MB);
  ushort* v_tiles = (ushort*)(ws + 13 * MB);
  ushort* Opart = (ushort*)(ws + 17 * MB);
  ushort* attT = xnT;  // alias: xnT dead after k_qkv

  k_stats1<<<512, 256, 0, stream>>>(x, part);
  k_castw<<<1025, 256, 0, stream>>>(qw, kw, vw, ow, wqkv, wo, part, stat);
  k_norm_t<<<dim3(128, 4), 256, 0, stream>>>(x, gw, gb, stat, xnT);
  k_qkv<<<dim3(128, 12), 256, 0, stream>>>(xnT, wqkv, qbv, kbv, vbv, qT, kT, v_tiles);
  k_attn<<<256, 256, 0, stream>>>(qT, kT, v_tiles, Opart, mpart, lpart);
  k_combine<<<NSP / 8, 256, 0, stream>>>(Opart, mpart, lpart, attT);
  k_final<<<dim3(128, 4), 256, 0, stream>>>(attT, wo, obv, x, gw, gb, stat, out);
}

// Round 12
// 135.521 us; speedup vs baseline: 4.4405x; 4.4405x over previous
//
#include <hip/hip_runtime.h>
#include <hip/hip_bf16.h>
#include <cstdint>

// Problem constants: B=1, C=256, F=8, H=32, W=32 -> N = 8192 spatial.
#define NSP 8192
#define CCH 256
#define KBLK 32
#define NSPLIT 8
#define KEYS_PER_SPLIT 1024
#define NTILES 32  // KEYS_PER_SPLIT / KBLK

typedef __attribute__((ext_vector_type(4))) float f32x4;
typedef __attribute__((ext_vector_type(16))) float f32x16;
typedef __attribute__((ext_vector_type(8))) short bf16x8;
typedef __attribute__((ext_vector_type(2))) unsigned int u32x2;

__device__ __forceinline__ ushort f2bf(float f) {
  union { float f; uint32_t u; } v; v.f = f;
  uint32_t r = (v.u + 0x7FFFu + ((v.u >> 16) & 1u)) >> 16;
  return (ushort)r;
}
__device__ __forceinline__ float bf2f(ushort u) {
  union { uint32_t u; float f; } v; v.u = ((uint32_t)u) << 16; return v.f;
}
__device__ __forceinline__ uint32_t pk2bf(float lo, float hi) {
  __hip_bfloat162 h = __float22bfloat162_rn({lo, hi});
  union { __hip_bfloat162 h; uint32_t u; } c; c.h = h; return c.u;
}

// global -> LDS direct copy, 16B per lane. LDS dest must be wave-uniform base.
__device__ __forceinline__ void gload_lds16(const void* g, void* l) {
  auto gp = (const __attribute__((address_space(1))) uint32_t*)(uintptr_t)g;
  auto lp = (__attribute__((address_space(3))) uint32_t*)(uint32_t)(uintptr_t)l;
  __builtin_amdgcn_global_load_lds(gp, lp, 16, 0, 0);
}

// exchange: swaps hi 32 lanes of a with lo 32 lanes of b
__device__ __forceinline__ void perm32swap(uint32_t& a, uint32_t& b) {
#if __has_builtin(__builtin_amdgcn_permlane32_swap)
  u32x2 r = __builtin_amdgcn_permlane32_swap(a, b, false, false);
  a = r[0]; b = r[1];
#else
  uint32_t sa = __shfl_xor((int)a, 32), sb = __shfl_xor((int)b, 32);
  bool lo = (threadIdx.x & 63) < 32;
  uint32_t na = lo ? a : sb;
  uint32_t nb = lo ? sa : b;
  a = na; b = nb;
#endif
}

// ---------------- K1: per-block partial sum/sumsq over x (2M floats) --------
__global__ __launch_bounds__(256) void k_stats1(const float* __restrict__ x,
                                                float* __restrict__ part) {
  int t = threadIdx.x, b = blockIdx.x;
  float s = 0.f, ss = 0.f;
  const float4* x4 = (const float4*)x;
  for (int i = 0; i < 4; ++i) {
    float4 v = x4[(size_t)i * 131072 + b * 256 + t];
    s += v.x + v.y + v.z + v.w;
    ss += v.x * v.x + v.y * v.y + v.z * v.z + v.w * v.w;
  }
  for (int m = 1; m < 64; m <<= 1) { s += __shfl_xor(s, m); ss += __shfl_xor(ss, m); }
  __shared__ float ls[4], lss[4];
  int w = t >> 6, lane = t & 63;
  if (lane == 0) { ls[w] = s; lss[w] = ss; }
  __syncthreads();
  if (t == 0) {
    part[b * 2 + 0] = ls[0] + ls[1] + ls[2] + ls[3];
    part[b * 2 + 1] = lss[0] + lss[1] + lss[2] + lss[3];
  }
}

// ---------------- K2: cast weights to bf16; block 1024 finalizes stats ------
__global__ __launch_bounds__(256) void k_castw(const float* __restrict__ qw, const float* __restrict__ kw,
                                               const float* __restrict__ vw, const float* __restrict__ ow,
                                               ushort* __restrict__ wqkv, ushort* __restrict__ wo,
                                               const float* __restrict__ part, float* __restrict__ stat) {
  if (blockIdx.x == 1024) {  // stats finalize
    int t = threadIdx.x;
    float s = 0.f, ss = 0.f;
    for (int i = t; i < 512; i += 256) { s += part[i * 2]; ss += part[i * 2 + 1]; }
    for (int m = 1; m < 64; m <<= 1) { s += __shfl_xor(s, m); ss += __shfl_xor(ss, m); }
    __shared__ float ls[4], lss[4];
    int w = t >> 6, lane = t & 63;
    if (lane == 0) { ls[w] = s; lss[w] = ss; }
    __syncthreads();
    if (t == 0) {
      float sum = ls[0] + ls[1] + ls[2] + ls[3];
      float ssum = lss[0] + lss[1] + lss[2] + lss[3];
      float mean = sum * (1.f / 2097152.f);
      float var = ssum * (1.f / 2097152.f) - mean * mean;
      stat[0] = mean;
      stat[1] = rsqrtf(var + 1e-5f);
    }
    return;
  }
  int idx = blockIdx.x * 256 + threadIdx.x;  // 262144 total
  if (idx < 65536) wqkv[idx] = f2bf(qw[idx]);
  else if (idx < 131072) wqkv[idx] = f2bf(kw[idx - 65536]);
  else if (idx < 196608) wqkv[idx] = f2bf(vw[idx - 131072]);
  else wo[idx - 196608] = f2bf(ow[idx - 196608]);
}

// ---------------- K3: normalize + transpose -> xnT bf16 [8192][256] ---------
__global__ __launch_bounds__(256) void k_norm_t(const float* __restrict__ x,
                                                const float* __restrict__ gw, const float* __restrict__ gb,
                                                const float* __restrict__ stat, ushort* __restrict__ xnT) {
  __shared__ float tile[64][66];
  int n0 = blockIdx.x * 64, c0 = blockIdx.y * 64;
  int t = threadIdx.x, colr = t & 63, rq = t >> 6;
  float mean = stat[0], rinv = stat[1];
  for (int rr = 0; rr < 16; ++rr) {
    int row = rr * 4 + rq;  // c-local
    int c = c0 + row;
    float v = x[(size_t)c * NSP + n0 + colr];
    tile[row][colr] = (v - mean) * rinv * gw[c] + gb[c];
  }
  __syncthreads();
  for (int rr = 0; rr < 16; ++rr) {
    int rowW = rr * 4 + rq;  // n-local
    xnT[(size_t)(n0 + rowW) * 256 + c0 + colr] = f2bf(tile[colr][rowW]);
  }
}

// ---------------- K4: QKV GEMM -> qT(scaled)/kT [8192][256],
//                  V packed per key-tile: v_tiles[256 tile][4 slot][256 c][8 m]
__global__ __launch_bounds__(256) void k_qkv(const ushort* __restrict__ xnT, const ushort* __restrict__ wqkv,
                                             const float* __restrict__ qb, const float* __restrict__ kb,
                                             const float* __restrict__ vb,
                                             ushort* __restrict__ qT, ushort* __restrict__ kT,
                                             ushort* __restrict__ v_tiles) {
  __shared__ ushort tile[64][80];  // V transpose bounce (160B rows, 16B aligned)
  int nb = blockIdx.x, ob = blockIdx.y;
  int w = threadIdx.x >> 6, lane = threadIdx.x & 63;
  int l16 = lane & 15, kgrp = lane >> 4;
  int n_row = nb * 64 + w * 16 + l16;
  bf16x8 a[8];
  const bf16x8* arow = (const bf16x8*)(xnT + (size_t)n_row * 256);
  for (int ks = 0; ks < 8; ++ks) a[ks] = arow[ks * 4 + kgrp];
  f32x4 acc[4];
  for (int ct = 0; ct < 4; ++ct) {
    int o = ob * 64 + ct * 16 + l16;
    const bf16x8* brow = (const bf16x8*)(wqkv + (size_t)o * 256);
    f32x4 c = {0.f, 0.f, 0.f, 0.f};
    for (int ks = 0; ks < 8; ++ks)
      c = __builtin_amdgcn_mfma_f32_16x16x32_bf16(a[ks], brow[ks * 4 + kgrp], c, 0, 0, 0);
    acc[ct] = c;
  }
  const float SCALE = 0.0625f * 1.44269504088896340736f;  // (1/sqrt(C)) * log2(e)
  if (ob < 8) {  // q / k outputs
    for (int ct = 0; ct < 4; ++ct) {
      int o = ob * 64 + ct * 16 + l16;
      for (int r = 0; r < 4; ++r) {
        int n = nb * 64 + w * 16 + kgrp * 4 + r;
        float v = acc[ct][r];
        if (o < 256) qT[(size_t)n * 256 + o] = f2bf((v + qb[o]) * SCALE);
        else kT[(size_t)n * 256 + (o - 256)] = f2bf(v + kb[o - 256]);
      }
    }
  } else {  // v outputs: bounce via LDS, emit tile-packed layout, coalesced
    for (int ct = 0; ct < 4; ++ct) {
      int o_l = ct * 16 + l16;
      for (int r = 0; r < 4; ++r) {
        int n_l = w * 16 + kgrp * 4 + r;
        tile[o_l][n_l] = f2bf(acc[ct][r] + vb[(ob - 8) * 64 + o_l]);
      }
    }
    __syncthreads();
    // v_tiles element (t, s, c, m) at ushort offset t*8192 + s*2048 + c*8 + m
    for (int j = 0; j < 2; ++j) {
      int idx = j * 256 + threadIdx.x;          // 512 stores of 16B
      int tile_l = idx >> 8, slot = (idx >> 6) & 3, c_l = idx & 63;
      size_t off = (size_t)(nb * 2 + tile_l) * 8192 + slot * 2048 +
                   (size_t)((ob - 8) * 64 + c_l) * 8;
      *(uint4*)((char*)v_tiles + off * 2) = *(const uint4*)&tile[c_l][tile_l * 32 + slot * 8];
    }
  }
}

// ---------------- K5: flash attention, cross-tile pipelined (r10 best) ------
// grid 256 = 1 block/CU (32 qblk x 8 splits, split = bid&7 -> XCD-exact).
// 512 threads (8 waves), wave owns 32 q (QBLK=256). LDS 64KB: K dbuf + V dbuf.
// Pipeline: iter tt computes PV(tt-1) INTERLEAVED with QK^T(tt) in one MFMA
// cluster (PV's 8 independent acc chains hide QK's serial dependent chain),
// then softmax(tt)->pf. Stage distance 1: K(tt+1), V(tt) issued at iter tt.
__global__ __launch_bounds__(512, 2) void k_attn(const ushort* __restrict__ qT, const ushort* __restrict__ kT,
                                                 const ushort* __restrict__ v_tiles,
                                                 ushort* __restrict__ Opart, float* __restrict__ mpart,
                                                 float* __restrict__ lpart) {
  __shared__ __align__(16) ushort SMEM[32768];  // 64 KB
  ushort* k_lds = SMEM;          // 2 x 8192: [32 key][256 c], 16B slots XOR-swz by key&7
  ushort* v_lds = SMEM + 16384;  // 2 x 8192: [slot s<4][256 c][8 m] (linear tile image)

  int bid = blockIdx.x;
  int split = bid & 7, qblk = bid >> 3;
  int t = threadIdx.x, w = t >> 6, lane = t & 63;
  int l31 = lane & 31, lhi = lane >> 5, l7 = lane & 7;
  int q0w = qblk * 256 + w * 32;

  // Q as B-operand fragments: lane holds q=l31, channels cs*16 + lhi*8 + j
  bf16x8 qf[16];
  {
    const char* qbase = (const char*)qT + (size_t)(q0w + l31) * 512;
#pragma unroll
    for (int cs = 0; cs < 16; ++cs)
      qf[cs] = *(const bf16x8*)(qbase + cs * 32 + lhi * 16);
  }

  f32x16 acc[8] = {};                 // O[c][q]: 8 blocks of 32 channels (AGPRs)
  float m_r = -1e30f, l_p = 0.f;      // per-lane (query q = l31)
  bf16x8 pf0, pf1;                    // P fragments of the previous tile

  const char* kT_b = (const char*)kT + (size_t)split * KEYS_PER_SPLIT * 512;
  const char* v_b = (const char*)v_tiles + (size_t)split * KEYS_PER_SPLIT * 512;

  // stage K(tt) -> kbuf[tt&1], V(tt) -> vbuf[tt&1]; 2+2 gload_lds per wave
  auto STAGE_K = [&](int tt) {
    const char* ksrc = kT_b + (size_t)tt * KBLK * 512;
    char* kdst = (char*)(k_lds + (tt & 1) * 8192) + w * 2048;
#pragma unroll
    for (int i = 0; i < 2; ++i) {
      int keyloc = w * 4 + i * 2 + lhi;
      int srcoff = keyloc * 512 + ((l31 ^ (keyloc & 7)) << 4);
      gload_lds16(ksrc + srcoff, kdst + i * 1024);
    }
  };
  auto STAGE_V = [&](int tt) {
    char* vdst = (char*)(v_lds + (tt & 1) * 8192) + w * 2048;
    const char* vsrc = v_b + (size_t)tt * 16384 + w * 2048;
#pragma unroll
    for (int i = 0; i < 2; ++i)
      gload_lds16(vsrc + i * 1024 + lane * 16, vdst + i * 1024);
  };

  // softmax + pack: consumes S0, updates m_r/l_p/pf0/pf1 (defer-max fast path)
  auto SOFTMAX_PACK = [&](f32x16& S0) {
    float x0 = fmaxf(S0[0], S0[1]), x1 = fmaxf(S0[2], S0[3]);
    float x2 = fmaxf(S0[4], S0[5]), x3 = fmaxf(S0[6], S0[7]);
    float x4 = fmaxf(S0[8], S0[9]), x5 = fmaxf(S0[10], S0[11]);
    float x6 = fmaxf(S0[12], S0[13]), x7 = fmaxf(S0[14], S0[15]);
    float pm = fmaxf(fmaxf(fmaxf(x0, x1), fmaxf(x2, x3)),
                     fmaxf(fmaxf(x4, x5), fmaxf(x6, x7)));
    pm = fmaxf(pm, __shfl_xor(pm, 32));
    if (!__all(pm <= m_r + 8.f)) {   // defer-max slow path (rare)
      float mn = fmaxf(m_r, pm);
      float alpha = __builtin_amdgcn_exp2f(m_r - mn);
      m_r = mn;
      l_p *= alpha;
#pragma unroll
      for (int cb = 0; cb < 8; ++cb)
#pragma unroll
        for (int r = 0; r < 16; ++r) acc[cb][r] *= alpha;
    }
    {
      float t0s = 0.f, t1s = 0.f, t2s = 0.f, t3s = 0.f;
#pragma unroll
      for (int r = 0; r < 16; ++r) {
        S0[r] = __builtin_amdgcn_exp2f(S0[r] - m_r);
        if (r < 4) t0s += S0[r];
        else if (r < 8) t1s += S0[r];
        else if (r < 12) t2s += S0[r];
        else t3s += S0[r];
      }
      l_p += (t0s + t1s) + (t2s + t3s);
    }
    union { uint32_t w[4]; bf16x8 v; } u;
    {
      uint32_t x = pk2bf(S0[0], S0[1]), y = pk2bf(S0[4], S0[5]);
      perm32swap(x, y);
      uint32_t x2_ = pk2bf(S0[2], S0[3]), y2 = pk2bf(S0[6], S0[7]);
      perm32swap(x2_, y2);
      u.w[0] = x; u.w[1] = x2_; u.w[2] = y; u.w[3] = y2;
      pf0 = u.v;
    }
    {
      uint32_t x = pk2bf(S0[8], S0[9]), y = pk2bf(S0[12], S0[13]);
      perm32swap(x, y);
      uint32_t x2_ = pk2bf(S0[10], S0[11]), y2 = pk2bf(S0[14], S0[15]);
      perm32swap(x2_, y2);
      u.w[0] = x; u.w[1] = x2_; u.w[2] = y; u.w[3] = y2;
      pf1 = u.v;
    }
  };

  STAGE_K(0);  // prologue

  // ---- iter 0 (peeled): QK^T(0) only ----
  asm volatile("s_waitcnt vmcnt(0) lgkmcnt(0)" ::: "memory");
  __builtin_amdgcn_s_barrier();
  __builtin_amdgcn_sched_barrier(0);
  STAGE_K(1);
  STAGE_V(0);
  {
    const ushort* kl = k_lds;  // buf 0
    f32x16 S0 = {};
    __builtin_amdgcn_s_setprio(1);
#pragma unroll
    for (int cs = 0; cs < 16; ++cs) {
      int slot = (cs * 2 + lhi) ^ l7;
      bf16x8 a0 = *(const bf16x8*)(kl + l31 * 256 + slot * 8);
      S0 = __builtin_amdgcn_mfma_f32_32x32x16_bf16(a0, qf[cs], S0, 0, 0, 0);
    }
    __builtin_amdgcn_s_setprio(0);
    SOFTMAX_PACK(S0);
  }

#pragma unroll 1
  for (int tt = 1; tt < NTILES; ++tt) {
    // K(tt), V(tt-1) staged last iter; buffers we overwrite were read last iter
    asm volatile("s_waitcnt vmcnt(0) lgkmcnt(0)" ::: "memory");
    __builtin_amdgcn_s_barrier();
    __builtin_amdgcn_sched_barrier(0);
    if (tt + 1 < NTILES) STAGE_K(tt + 1);
    STAGE_V(tt);

    // ---- interleaved cluster: PV(tt-1) + QK^T(tt) ----
    const ushort* kl = k_lds + (tt & 1) * 8192;
    const ushort* vl = v_lds + ((tt - 1) & 1) * 8192;
    f32x16 S0 = {};
    __builtin_amdgcn_s_setprio(1);
#pragma unroll
    for (int cb = 0; cb < 8; ++cb) {
      bf16x8 va0 = *(const bf16x8*)(vl + (0 + lhi) * 2048 + (cb * 32 + l31) * 8);
      acc[cb] = __builtin_amdgcn_mfma_f32_32x32x16_bf16(va0, pf0, acc[cb], 0, 0, 0);
      {
        int cs = 2 * cb;
        int slot = (cs * 2 + lhi) ^ l7;
        bf16x8 ka = *(const bf16x8*)(kl + l31 * 256 + slot * 8);
        S0 = __builtin_amdgcn_mfma_f32_32x32x16_bf16(ka, qf[cs], S0, 0, 0, 0);
      }
      bf16x8 va1 = *(const bf16x8*)(vl + (2 + lhi) * 2048 + (cb * 32 + l31) * 8);
      acc[cb] = __builtin_amdgcn_mfma_f32_32x32x16_bf16(va1, pf1, acc[cb], 0, 0, 0);
      {
        int cs = 2 * cb + 1;
        int slot = (cs * 2 + lhi) ^ l7;
        bf16x8 ka = *(const bf16x8*)(kl + l31 * 256 + slot * 8);
        S0 = __builtin_amdgcn_mfma_f32_32x32x16_bf16(ka, qf[cs], S0, 0, 0, 0);
      }
    }
    __builtin_amdgcn_s_setprio(0);
    SOFTMAX_PACK(S0);
  }

  // ---- drain pipeline: PV(NTILES-1) ----
  asm volatile("s_waitcnt vmcnt(0) lgkmcnt(0)" ::: "memory");
  __builtin_amdgcn_s_barrier();
  {
    const ushort* vl = v_lds + ((NTILES - 1) & 1) * 8192;
    __builtin_amdgcn_s_setprio(1);
#pragma unroll
    for (int cb = 0; cb < 8; ++cb) {
      bf16x8 va0 = *(const bf16x8*)(vl + (0 + lhi) * 2048 + (cb * 32 + l31) * 8);
      acc[cb] = __builtin_amdgcn_mfma_f32_32x32x16_bf16(va0, pf0, acc[cb], 0, 0, 0);
      bf16x8 va1 = *(const bf16x8*)(vl + (2 + lhi) * 2048 + (cb * 32 + l31) * 8);
      acc[cb] = __builtin_amdgcn_mfma_f32_32x32x16_bf16(va1, pf1, acc[cb], 0, 0, 0);
    }
    __builtin_amdgcn_s_setprio(0);
  }

  // all waves done with LDS before reusing it as epilogue scratch
  asm volatile("s_waitcnt lgkmcnt(0)" ::: "memory");
  __builtin_amdgcn_s_barrier();

  // ---- epilogue: l reduce, O -> LDS transpose (64-c chunks) -> coalesced ----
  float l_tot = l_p + __shfl_xor(l_p, 32);

  // per-wave scratch: 32 q-rows x 144B (64 c x 2B + 16B pad); 8 waves = 36KB
  char* eb = (char*)SMEM + w * 4608;
  size_t gq0 = (size_t)split * NSP + q0w;
#pragma unroll
  for (int ch = 0; ch < 4; ++ch) {
#pragma unroll
    for (int cb2 = 0; cb2 < 2; ++cb2) {
      int cb = ch * 2 + cb2;
#pragma unroll
      for (int g = 0; g < 4; ++g) {
        int cl = cb2 * 32 + g * 8 + 4 * lhi;
        *(uint32_t*)(eb + l31 * 144 + cl * 2) = pk2bf(acc[cb][g * 4 + 0], acc[cb][g * 4 + 1]);
        *(uint32_t*)(eb + l31 * 144 + cl * 2 + 4) = pk2bf(acc[cb][g * 4 + 2], acc[cb][g * 4 + 3]);
      }
    }
    asm volatile("s_waitcnt lgkmcnt(0)" ::: "memory");
    __builtin_amdgcn_sched_barrier(0);
#pragma unroll
    for (int i = 0; i < 4; ++i) {
      int flat = i * 1024 + lane * 16;
      int qr = flat >> 7, off = flat & 127;
      uint4 val = *(const uint4*)(eb + qr * 144 + off);
      *(uint4*)((char*)Opart + (gq0 + qr) * 512 + ch * 128 + off) = val;
    }
    asm volatile("s_waitcnt lgkmcnt(0)" ::: "memory");
    __builtin_amdgcn_sched_barrier(0);
  }
  if (lane < 32) {
    int q = q0w + l31;
    mpart[split * NSP + q] = m_r;
    lpart[split * NSP + q] = l_tot;
  }
}

// ---------------- K6: combine split partials -> attT bf16 [8192][256] -------
// 8 q-rows per block; each thread handles 8 channels via bf16x8 (vectorized).
__global__ __launch_bounds__(256) void k_combine(const ushort* __restrict__ Opart,
                                                 const float* __restrict__ mpart,
                                                 const float* __restrict__ lpart,
                                                 ushort* __restrict__ attT) {
  int q = blockIdx.x * 8 + (threadIdx.x >> 5);
  int c8 = threadIdx.x & 31;  // channels c8*8 .. c8*8+7
  float M = -1e30f;
#pragma unroll
  for (int s = 0; s < NSPLIT; ++s) M = fmaxf(M, mpart[s * NSP + q]);
  float L = 0.f;
  float av[8] = {};
#pragma unroll
  for (int s = 0; s < NSPLIT; ++s) {
    float ws = __builtin_amdgcn_exp2f(mpart[s * NSP + q] - M);
    L += ws * lpart[s * NSP + q];
    bf16x8 o = *(const bf16x8*)(Opart + ((size_t)s * NSP + q) * 256 + c8 * 8);
#pragma unroll
    for (int j = 0; j < 8; ++j) av[j] += ws * bf2f((ushort)o[j]);
  }
  float rL = 1.f / L;
  uint4 outv;
  outv.x = pk2bf(av[0] * rL, av[1] * rL);
  outv.y = pk2bf(av[2] * rL, av[3] * rL);
  outv.z = pk2bf(av[4] * rL, av[5] * rL);
  outv.w = pk2bf(av[6] * rL, av[7] * rL);
  *(uint4*)(attT + (size_t)q * 256 + c8 * 8) = outv;
}

// ---------------- K7: out = xn + ow @ att + ob ------------------------------
__global__ __launch_bounds__(256) void k_final(const ushort* __restrict__ attT, const ushort* __restrict__ wo,
                                               const float* __restrict__ ob, const float* __restrict__ x,
                                               const float* __restrict__ gw, const float* __restrict__ gb,
                                               const float* __restrict__ stat, float* __restrict__ out) {
  int nb = blockIdx.x, obk = blockIdx.y;
  int w = threadIdx.x >> 6, lane = threadIdx.x & 63;
  int l16 = lane & 15, kgrp = lane >> 4;
  int orow = obk * 64 + w * 16 + l16;
  bf16x8 a[8];
  const bf16x8* arow = (const bf16x8*)(wo + (size_t)orow * 256);
  for (int ks = 0; ks < 8; ++ks) a[ks] = arow[ks * 4 + kgrp];
  float mean = stat[0], rinv = stat[1];
  f32x4 acc[4];
  for (int ct = 0; ct < 4; ++ct) {
    int n = nb * 64 + ct * 16 + l16;
    const bf16x8* brow = (const bf16x8*)(attT + (size_t)n * 256);
    f32x4 c = {0.f, 0.f, 0.f, 0.f};
    for (int ks = 0; ks < 8; ++ks)
      c = __builtin_amdgcn_mfma_f32_16x16x32_bf16(a[ks], brow[ks * 4 + kgrp], c, 0, 0, 0);
    acc[ct] = c;
  }
  for (int ct = 0; ct < 4; ++ct) {
    for (int r = 0; r < 4; ++r) {
      int o = obk * 64 + w * 16 + kgrp * 4 + r;
      int n = nb * 64 + ct * 16 + l16;
      float xv = x[(size_t)o * NSP + n];
      float xn = (xv - mean) * rinv * gw[o] + gb[o];
      out[(size_t)o * NSP + n] = xn + acc[ct][r] + ob[o];
    }
  }
}

extern "C" void kernel_launch(void* const* d_in, const int* in_sizes, int n_in,
                              void* d_out, int out_size, void* d_ws, size_t ws_size,
                              hipStream_t stream) {
  const float* x = (const float*)d_in[0];
  const float* gw = (const float*)d_in[1];
  const float* gb = (const float*)d_in[2];
  const float* qw = (const float*)d_in[3];
  const float* qbv = (const float*)d_in[4];
  const float* kw = (const float*)d_in[5];
  const float* kbv = (const float*)d_in[6];
  const float* vw = (const float*)d_in[7];
  const float* vbv = (const float*)d_in[8];
  const float* ow = (const float*)d_in[9];
  const float* obv = (const float*)d_in[10];
  float* out = (float*)d_out;
  char* ws = (char*)d_ws;
  const size_t KB = 1024, MB = 1048576;
  // region plan (high-water 49 MB):
  //  0..4K      part
  //  60K        stat
  //  64..448K   wqkv (dead after k_qkv) -> mpart (256K) overlays
  //  448..576K  wo (live until k_final)
  //  576..832K  lpart
  //  1..5MB     xnT (k_norm_t->k_qkv) -> attT (k_combine->k_final)
  //  5..9MB     qT
  //  9..13MB    kT
  //  13..17MB   v_tiles [256 tile][16KB]
  //  17..49MB   Opart (8 splits, bf16)
  float* part = (float*)(ws);
  float* stat = (float*)(ws + 60 * KB);
  ushort* wqkv = (ushort*)(ws + 64 * KB);
  ushort* wo = (ushort*)(ws + 448 * KB);
  float* mpart = (float*)(ws + 64 * KB);    // overlays wqkv (dead by k_attn)
  float* lpart = (float*)(ws + 576 * KB);
  ushort* xnT = (ushort*)(ws + 1 * MB);
  ushort* qT = (ushort*)(ws + 5 * MB);
  ushort* kT = (ushort*)(ws + 9 * MB);
  ushort* v_tiles = (ushort*)(ws + 13 * MB);
  ushort* Opart = (ushort*)(ws + 17 * MB);
  ushort* attT = xnT;  // alias: xnT dead after k_qkv

  k_stats1<<<512, 256, 0, stream>>>(x, part);
  k_castw<<<1025, 256, 0, stream>>>(qw, kw, vw, ow, wqkv, wo, part, stat);
  k_norm_t<<<dim3(128, 4), 256, 0, stream>>>(x, gw, gb, stat, xnT);
  k_qkv<<<dim3(128, 12), 256, 0, stream>>>(xnT, wqkv, qbv, kbv, vbv, qT, kT, v_tiles);
  k_attn<<<256, 512, 0, stream>>>(qT, kT, v_tiles, Opart, mpart, lpart);
  k_combine<<<NSP / 8, 256, 0, stream>>>(Opart, mpart, lpart, attT);
  k_final<<<dim3(128, 4), 256, 0, stream>>>(attT, wo, obv, x, gw, gb, stat, out);
}

// Round 13
// 133.798 us; speedup vs baseline: 4.4977x; 1.0129x over previous
//
#include <hip/hip_runtime.h>
#include <hip/hip_bf16.h>
#include <cstdint>

// Problem constants: B=1, C=256, F=8, H=32, W=32 -> N = 8192 spatial.
#define NSP 8192
#define CCH 256
#define KBLK 32
#define NSPLIT 8
#define KEYS_PER_SPLIT 1024
#define NTILES 32  // KEYS_PER_SPLIT / KBLK

typedef __attribute__((ext_vector_type(4))) float f32x4;
typedef __attribute__((ext_vector_type(16))) float f32x16;
typedef __attribute__((ext_vector_type(8))) short bf16x8;
typedef __attribute__((ext_vector_type(2))) unsigned int u32x2;

__device__ __forceinline__ ushort f2bf(float f) {
  union { float f; uint32_t u; } v; v.f = f;
  uint32_t r = (v.u + 0x7FFFu + ((v.u >> 16) & 1u)) >> 16;
  return (ushort)r;
}
__device__ __forceinline__ float bf2f(ushort u) {
  union { uint32_t u; float f; } v; v.u = ((uint32_t)u) << 16; return v.f;
}
__device__ __forceinline__ uint32_t pk2bf(float lo, float hi) {
  __hip_bfloat162 h = __float22bfloat162_rn({lo, hi});
  union { __hip_bfloat162 h; uint32_t u; } c; c.h = h; return c.u;
}

// global -> LDS direct copy, 16B per lane. LDS dest must be wave-uniform base.
__device__ __forceinline__ void gload_lds16(const void* g, void* l) {
  auto gp = (const __attribute__((address_space(1))) uint32_t*)(uintptr_t)g;
  auto lp = (__attribute__((address_space(3))) uint32_t*)(uint32_t)(uintptr_t)l;
  __builtin_amdgcn_global_load_lds(gp, lp, 16, 0, 0);
}

// exchange: swaps hi 32 lanes of a with lo 32 lanes of b
__device__ __forceinline__ void perm32swap(uint32_t& a, uint32_t& b) {
#if __has_builtin(__builtin_amdgcn_permlane32_swap)
  u32x2 r = __builtin_amdgcn_permlane32_swap(a, b, false, false);
  a = r[0]; b = r[1];
#else
  uint32_t sa = __shfl_xor((int)a, 32), sb = __shfl_xor((int)b, 32);
  bool lo = (threadIdx.x & 63) < 32;
  uint32_t na = lo ? a : sb;
  uint32_t nb = lo ? sa : b;
  a = na; b = nb;
#endif
}

// ---------------- K1: per-block partial sum/sumsq over x (2M floats) --------
__global__ __launch_bounds__(256) void k_stats1(const float* __restrict__ x,
                                                float* __restrict__ part) {
  int t = threadIdx.x, b = blockIdx.x;
  float s = 0.f, ss = 0.f;
  const float4* x4 = (const float4*)x;
  for (int i = 0; i < 4; ++i) {
    float4 v = x4[(size_t)i * 131072 + b * 256 + t];
    s += v.x + v.y + v.z + v.w;
    ss += v.x * v.x + v.y * v.y + v.z * v.z + v.w * v.w;
  }
  for (int m = 1; m < 64; m <<= 1) { s += __shfl_xor(s, m); ss += __shfl_xor(ss, m); }
  __shared__ float ls[4], lss[4];
  int w = t >> 6, lane = t & 63;
  if (lane == 0) { ls[w] = s; lss[w] = ss; }
  __syncthreads();
  if (t == 0) {
    part[b * 2 + 0] = ls[0] + ls[1] + ls[2] + ls[3];
    part[b * 2 + 1] = lss[0] + lss[1] + lss[2] + lss[3];
  }
}

// ---------------- K2: cast weights to bf16; block 1024 finalizes stats ------
__global__ __launch_bounds__(256) void k_castw(const float* __restrict__ qw, const float* __restrict__ kw,
                                               const float* __restrict__ vw, const float* __restrict__ ow,
                                               ushort* __restrict__ wqkv, ushort* __restrict__ wo,
                                               const float* __restrict__ part, float* __restrict__ stat) {
  if (blockIdx.x == 1024) {  // stats finalize
    int t = threadIdx.x;
    float s = 0.f, ss = 0.f;
    for (int i = t; i < 512; i += 256) { s += part[i * 2]; ss += part[i * 2 + 1]; }
    for (int m = 1; m < 64; m <<= 1) { s += __shfl_xor(s, m); ss += __shfl_xor(ss, m); }
    __shared__ float ls[4], lss[4];
    int w = t >> 6, lane = t & 63;
    if (lane == 0) { ls[w] = s; lss[w] = ss; }
    __syncthreads();
    if (t == 0) {
      float sum = ls[0] + ls[1] + ls[2] + ls[3];
      float ssum = lss[0] + lss[1] + lss[2] + lss[3];
      float mean = sum * (1.f / 2097152.f);
      float var = ssum * (1.f / 2097152.f) - mean * mean;
      stat[0] = mean;
      stat[1] = rsqrtf(var + 1e-5f);
    }
    return;
  }
  int idx = blockIdx.x * 256 + threadIdx.x;  // 262144 total
  if (idx < 65536) wqkv[idx] = f2bf(qw[idx]);
  else if (idx < 131072) wqkv[idx] = f2bf(kw[idx - 65536]);
  else if (idx < 196608) wqkv[idx] = f2bf(vw[idx - 131072]);
  else wo[idx - 196608] = f2bf(ow[idx - 196608]);
}

// ---------------- K3: normalize + transpose -> xnT bf16 [8192][256] ---------
__global__ __launch_bounds__(256) void k_norm_t(const float* __restrict__ x,
                                                const float* __restrict__ gw, const float* __restrict__ gb,
                                                const float* __restrict__ stat, ushort* __restrict__ xnT) {
  __shared__ float tile[64][66];
  int n0 = blockIdx.x * 64, c0 = blockIdx.y * 64;
  int t = threadIdx.x, colr = t & 63, rq = t >> 6;
  float mean = stat[0], rinv = stat[1];
  for (int rr = 0; rr < 16; ++rr) {
    int row = rr * 4 + rq;  // c-local
    int c = c0 + row;
    float v = x[(size_t)c * NSP + n0 + colr];
    tile[row][colr] = (v - mean) * rinv * gw[c] + gb[c];
  }
  __syncthreads();
  for (int rr = 0; rr < 16; ++rr) {
    int rowW = rr * 4 + rq;  // n-local
    xnT[(size_t)(n0 + rowW) * 256 + c0 + colr] = f2bf(tile[colr][rowW]);
  }
}

// ---------------- K4: QKV GEMM -> qT [8192][256],
//   K packed per key-tile: k_tiles[256 tile][32 s][32 key][8]  (s = chan/8)
//   V packed per key-tile: v_tiles[256 tile][4 slot][256 c][8 m]
__global__ __launch_bounds__(256) void k_qkv(const ushort* __restrict__ xnT, const ushort* __restrict__ wqkv,
                                             const float* __restrict__ qb, const float* __restrict__ kb,
                                             const float* __restrict__ vb,
                                             ushort* __restrict__ qT, ushort* __restrict__ k_tiles,
                                             ushort* __restrict__ v_tiles) {
  __shared__ ushort tile[64][80];  // transpose bounce (160B rows, 16B aligned)
  int nb = blockIdx.x, ob = blockIdx.y;
  int w = threadIdx.x >> 6, lane = threadIdx.x & 63;
  int l16 = lane & 15, kgrp = lane >> 4;
  int n_row = nb * 64 + w * 16 + l16;
  bf16x8 a[8];
  const bf16x8* arow = (const bf16x8*)(xnT + (size_t)n_row * 256);
  for (int ks = 0; ks < 8; ++ks) a[ks] = arow[ks * 4 + kgrp];
  f32x4 acc[4];
  for (int ct = 0; ct < 4; ++ct) {
    int o = ob * 64 + ct * 16 + l16;
    const bf16x8* brow = (const bf16x8*)(wqkv + (size_t)o * 256);
    f32x4 c = {0.f, 0.f, 0.f, 0.f};
    for (int ks = 0; ks < 8; ++ks)
      c = __builtin_amdgcn_mfma_f32_16x16x32_bf16(a[ks], brow[ks * 4 + kgrp], c, 0, 0, 0);
    acc[ct] = c;
  }
  const float SCALE = 0.0625f * 1.44269504088896340736f;  // (1/sqrt(C)) * log2(e)
  if (ob < 4) {  // q outputs: direct scattered write
    for (int ct = 0; ct < 4; ++ct) {
      int o = ob * 64 + ct * 16 + l16;
      for (int r = 0; r < 4; ++r) {
        int n = nb * 64 + w * 16 + kgrp * 4 + r;
        qT[(size_t)n * 256 + o] = f2bf((acc[ct][r] + qb[o]) * SCALE);
      }
    }
  } else if (ob < 8) {  // k outputs: bounce [n][c], emit tile-packed transposed
    for (int ct = 0; ct < 4; ++ct) {
      int o_l = ct * 16 + l16;  // channel-local 0..63
      for (int r = 0; r < 4; ++r) {
        int n_l = w * 16 + kgrp * 4 + r;  // key-local 0..63
        tile[n_l][o_l] = f2bf(acc[ct][r] + kb[(ob - 4) * 64 + o_l]);
      }
    }
    __syncthreads();
    // k_tiles element (tile, s, key, j) = K[key][c = s*8+j]
    for (int j = 0; j < 2; ++j) {
      int idx = j * 256 + threadIdx.x;          // 512 granules of 16B
      int tile_l = idx >> 8, s = (idx >> 5) & 7, key = idx & 31;
      size_t off = (size_t)(nb * 2 + tile_l) * 16384 +
                   (size_t)((ob - 4) * 8 + s) * 512 + key * 16;
      *(uint4*)((char*)k_tiles + off) = *(const uint4*)&tile[tile_l * 32 + key][s * 8];
    }
  } else {  // v outputs: bounce [c][n], emit tile-packed layout, coalesced
    for (int ct = 0; ct < 4; ++ct) {
      int o_l = ct * 16 + l16;
      for (int r = 0; r < 4; ++r) {
        int n_l = w * 16 + kgrp * 4 + r;
        tile[o_l][n_l] = f2bf(acc[ct][r] + vb[(ob - 8) * 64 + o_l]);
      }
    }
    __syncthreads();
    // v_tiles element (t, s, c, m) at ushort offset t*8192 + s*2048 + c*8 + m
    for (int j = 0; j < 2; ++j) {
      int idx = j * 256 + threadIdx.x;          // 512 stores of 16B
      int tile_l = idx >> 8, slot = (idx >> 6) & 3, c_l = idx & 63;
      size_t off = (size_t)(nb * 2 + tile_l) * 8192 + slot * 2048 +
                   (size_t)((ob - 8) * 64 + c_l) * 8;
      *(uint4*)((char*)v_tiles + off * 2) = *(const uint4*)&tile[c_l][tile_l * 32 + slot * 8];
    }
  }
}

// ---------------- K5: flash attention, cross-tile pipelined -----------------
// grid 256 = 1 block/CU (32 qblk x 8 splits, split = bid&7 -> XCD-exact).
// 512 threads (8 waves), wave owns 32 q (QBLK=256). LDS 64KB: K dbuf + V dbuf.
// K tile-packed [s][key][8] -> QK reads are contiguous 1KB, conflict-free
// (the old [key][slot]+XOR layout was inherently 4-way bank conflicted).
// Pipeline: iter tt computes PV(tt-1) INTERLEAVED with QK^T(tt) in one MFMA
// cluster, then softmax(tt)->pf. Stage distance 1: K(tt+1), V(tt) at iter tt.
__global__ __launch_bounds__(512, 2) void k_attn(const ushort* __restrict__ qT, const ushort* __restrict__ k_tiles,
                                                 const ushort* __restrict__ v_tiles,
                                                 ushort* __restrict__ Opart, float* __restrict__ mpart,
                                                 float* __restrict__ lpart) {
  __shared__ __align__(16) ushort SMEM[32768];  // 64 KB
  ushort* k_lds = SMEM;          // 2 x 8192: [32 s][32 key][8] (linear tile image)
  ushort* v_lds = SMEM + 16384;  // 2 x 8192: [4 slot][256 c][8 m] (linear tile image)

  int bid = blockIdx.x;
  int split = bid & 7, qblk = bid >> 3;
  int t = threadIdx.x, w = t >> 6, lane = t & 63;
  int l31 = lane & 31, lhi = lane >> 5;
  int q0w = qblk * 256 + w * 32;

  // Q as B-operand fragments: lane holds q=l31, channels cs*16 + lhi*8 + j
  bf16x8 qf[16];
  {
    const char* qbase = (const char*)qT + (size_t)(q0w + l31) * 512;
#pragma unroll
    for (int cs = 0; cs < 16; ++cs)
      qf[cs] = *(const bf16x8*)(qbase + cs * 32 + lhi * 16);
  }

  f32x16 acc[8] = {};                 // O[c][q]: 8 blocks of 32 channels (AGPRs)
  float m_r = -1e30f, l_p = 0.f;      // per-lane (query q = l31)
  bf16x8 pf0, pf1;                    // P fragments of the previous tile

  const char* kT_b = (const char*)k_tiles + (size_t)split * KEYS_PER_SPLIT * 512;
  const char* v_b = (const char*)v_tiles + (size_t)split * KEYS_PER_SPLIT * 512;

  // stage K(tt) -> kbuf[tt&1], V(tt) -> vbuf[tt&1]; linear 16KB copies
  auto STAGE_K = [&](int tt) {
    const char* ksrc = kT_b + (size_t)tt * 16384 + w * 2048;
    char* kdst = (char*)(k_lds + (tt & 1) * 8192) + w * 2048;
#pragma unroll
    for (int i = 0; i < 2; ++i)
      gload_lds16(ksrc + i * 1024 + lane * 16, kdst + i * 1024);
  };
  auto STAGE_V = [&](int tt) {
    char* vdst = (char*)(v_lds + (tt & 1) * 8192) + w * 2048;
    const char* vsrc = v_b + (size_t)tt * 16384 + w * 2048;
#pragma unroll
    for (int i = 0; i < 2; ++i)
      gload_lds16(vsrc + i * 1024 + lane * 16, vdst + i * 1024);
  };

  // softmax + pack: consumes S0, updates m_r/l_p/pf0/pf1 (defer-max fast path)
  auto SOFTMAX_PACK = [&](f32x16& S0) {
    float x0 = fmaxf(S0[0], S0[1]), x1 = fmaxf(S0[2], S0[3]);
    float x2 = fmaxf(S0[4], S0[5]), x3 = fmaxf(S0[6], S0[7]);
    float x4 = fmaxf(S0[8], S0[9]), x5 = fmaxf(S0[10], S0[11]);
    float x6 = fmaxf(S0[12], S0[13]), x7 = fmaxf(S0[14], S0[15]);
    float pm = fmaxf(fmaxf(fmaxf(x0, x1), fmaxf(x2, x3)),
                     fmaxf(fmaxf(x4, x5), fmaxf(x6, x7)));
    pm = fmaxf(pm, __shfl_xor(pm, 32));
    if (!__all(pm <= m_r + 8.f)) {   // defer-max slow path (rare)
      float mn = fmaxf(m_r, pm);
      float alpha = __builtin_amdgcn_exp2f(m_r - mn);
      m_r = mn;
      l_p *= alpha;
#pragma unroll
      for (int cb = 0; cb < 8; ++cb)
#pragma unroll
        for (int r = 0; r < 16; ++r) acc[cb][r] *= alpha;
    }
    {
      float t0s = 0.f, t1s = 0.f, t2s = 0.f, t3s = 0.f;
#pragma unroll
      for (int r = 0; r < 16; ++r) {
        S0[r] = __builtin_amdgcn_exp2f(S0[r] - m_r);
        if (r < 4) t0s += S0[r];
        else if (r < 8) t1s += S0[r];
        else if (r < 12) t2s += S0[r];
        else t3s += S0[r];
      }
      l_p += (t0s + t1s) + (t2s + t3s);
    }
    union { uint32_t w[4]; bf16x8 v; } u;
    {
      uint32_t x = pk2bf(S0[0], S0[1]), y = pk2bf(S0[4], S0[5]);
      perm32swap(x, y);
      uint32_t x2_ = pk2bf(S0[2], S0[3]), y2 = pk2bf(S0[6], S0[7]);
      perm32swap(x2_, y2);
      u.w[0] = x; u.w[1] = x2_; u.w[2] = y; u.w[3] = y2;
      pf0 = u.v;
    }
    {
      uint32_t x = pk2bf(S0[8], S0[9]), y = pk2bf(S0[12], S0[13]);
      perm32swap(x, y);
      uint32_t x2_ = pk2bf(S0[10], S0[11]), y2 = pk2bf(S0[14], S0[15]);
      perm32swap(x2_, y2);
      u.w[0] = x; u.w[1] = x2_; u.w[2] = y; u.w[3] = y2;
      pf1 = u.v;
    }
  };

  STAGE_K(0);  // prologue

  // ---- iter 0 (peeled): QK^T(0) only ----
  asm volatile("s_waitcnt vmcnt(0) lgkmcnt(0)" ::: "memory");
  __builtin_amdgcn_s_barrier();
  __builtin_amdgcn_sched_barrier(0);
  STAGE_K(1);
  STAGE_V(0);
  {
    const ushort* kl = k_lds;  // buf 0
    f32x16 S0 = {};
    __builtin_amdgcn_s_setprio(1);
#pragma unroll
    for (int cs = 0; cs < 16; ++cs) {
      int slot = cs * 2 + lhi;
      bf16x8 a0 = *(const bf16x8*)(kl + slot * 256 + l31 * 8);
      S0 = __builtin_amdgcn_mfma_f32_32x32x16_bf16(a0, qf[cs], S0, 0, 0, 0);
    }
    __builtin_amdgcn_s_setprio(0);
    SOFTMAX_PACK(S0);
  }

#pragma unroll 1
  for (int tt = 1; tt < NTILES; ++tt) {
    // K(tt), V(tt-1) staged last iter; buffers we overwrite were read last iter
    asm volatile("s_waitcnt vmcnt(0) lgkmcnt(0)" ::: "memory");
    __builtin_amdgcn_s_barrier();
    __builtin_amdgcn_sched_barrier(0);
    if (tt + 1 < NTILES) STAGE_K(tt + 1);
    STAGE_V(tt);

    // ---- interleaved cluster: PV(tt-1) + QK^T(tt) ----
    const ushort* kl = k_lds + (tt & 1) * 8192;
    const ushort* vl = v_lds + ((tt - 1) & 1) * 8192;
    f32x16 S0 = {};
    __builtin_amdgcn_s_setprio(1);
#pragma unroll
    for (int cb = 0; cb < 8; ++cb) {
      bf16x8 va0 = *(const bf16x8*)(vl + (0 + lhi) * 2048 + (cb * 32 + l31) * 8);
      acc[cb] = __builtin_amdgcn_mfma_f32_32x32x16_bf16(va0, pf0, acc[cb], 0, 0, 0);
      {
        int slot = 4 * cb + lhi;
        bf16x8 ka = *(const bf16x8*)(kl + slot * 256 + l31 * 8);
        S0 = __builtin_amdgcn_mfma_f32_32x32x16_bf16(ka, qf[2 * cb], S0, 0, 0, 0);
      }
      bf16x8 va1 = *(const bf16x8*)(vl + (2 + lhi) * 2048 + (cb * 32 + l31) * 8);
      acc[cb] = __builtin_amdgcn_mfma_f32_32x32x16_bf16(va1, pf1, acc[cb], 0, 0, 0);
      {
        int slot = 4 * cb + 2 + lhi;
        bf16x8 ka = *(const bf16x8*)(kl + slot * 256 + l31 * 8);
        S0 = __builtin_amdgcn_mfma_f32_32x32x16_bf16(ka, qf[2 * cb + 1], S0, 0, 0, 0);
      }
    }
    __builtin_amdgcn_s_setprio(0);
    SOFTMAX_PACK(S0);
  }

  // ---- drain pipeline: PV(NTILES-1) ----
  asm volatile("s_waitcnt vmcnt(0) lgkmcnt(0)" ::: "memory");
  __builtin_amdgcn_s_barrier();
  {
    const ushort* vl = v_lds + ((NTILES - 1) & 1) * 8192;
    __builtin_amdgcn_s_setprio(1);
#pragma unroll
    for (int cb = 0; cb < 8; ++cb) {
      bf16x8 va0 = *(const bf16x8*)(vl + (0 + lhi) * 2048 + (cb * 32 + l31) * 8);
      acc[cb] = __builtin_amdgcn_mfma_f32_32x32x16_bf16(va0, pf0, acc[cb], 0, 0, 0);
      bf16x8 va1 = *(const bf16x8*)(vl + (2 + lhi) * 2048 + (cb * 32 + l31) * 8);
      acc[cb] = __builtin_amdgcn_mfma_f32_32x32x16_bf16(va1, pf1, acc[cb], 0, 0, 0);
    }
    __builtin_amdgcn_s_setprio(0);
  }

  // all waves done with LDS before reusing it as epilogue scratch
  asm volatile("s_waitcnt lgkmcnt(0)" ::: "memory");
  __builtin_amdgcn_s_barrier();

  // ---- epilogue: l reduce, O -> LDS transpose (64-c chunks) -> coalesced ----
  float l_tot = l_p + __shfl_xor(l_p, 32);

  // per-wave scratch: 32 q-rows x 144B (64 c x 2B + 16B pad); 8 waves = 36KB
  char* eb = (char*)SMEM + w * 4608;
  size_t gq0 = (size_t)split * NSP + q0w;
#pragma unroll
  for (int ch = 0; ch < 4; ++ch) {
#pragma unroll
    for (int cb2 = 0; cb2 < 2; ++cb2) {
      int cb = ch * 2 + cb2;
#pragma unroll
      for (int g = 0; g < 4; ++g) {
        int cl = cb2 * 32 + g * 8 + 4 * lhi;
        *(uint32_t*)(eb + l31 * 144 + cl * 2) = pk2bf(acc[cb][g * 4 + 0], acc[cb][g * 4 + 1]);
        *(uint32_t*)(eb + l31 * 144 + cl * 2 + 4) = pk2bf(acc[cb][g * 4 + 2], acc[cb][g * 4 + 3]);
      }
    }
    asm volatile("s_waitcnt lgkmcnt(0)" ::: "memory");
    __builtin_amdgcn_sched_barrier(0);
#pragma unroll
    for (int i = 0; i < 4; ++i) {
      int flat = i * 1024 + lane * 16;
      int qr = flat >> 7, off = flat & 127;
      uint4 val = *(const uint4*)(eb + qr * 144 + off);
      *(uint4*)((char*)Opart + (gq0 + qr) * 512 + ch * 128 + off) = val;
    }
    asm volatile("s_waitcnt lgkmcnt(0)" ::: "memory");
    __builtin_amdgcn_sched_barrier(0);
  }
  if (lane < 32) {
    int q = q0w + l31;
    mpart[split * NSP + q] = m_r;
    lpart[split * NSP + q] = l_tot;
  }
}

// ---------------- K6: combine split partials -> attT bf16 [8192][256] -------
// 8 q-rows per block; each thread handles 8 channels via bf16x8 (vectorized).
__global__ __launch_bounds__(256) void k_combine(const ushort* __restrict__ Opart,
                                                 const float* __restrict__ mpart,
                                                 const float* __restrict__ lpart,
                                                 ushort* __restrict__ attT) {
  int q = blockIdx.x * 8 + (threadIdx.x >> 5);
  int c8 = threadIdx.x & 31;  // channels c8*8 .. c8*8+7
  float M = -1e30f;
#pragma unroll
  for (int s = 0; s < NSPLIT; ++s) M = fmaxf(M, mpart[s * NSP + q]);
  float L = 0.f;
  float av[8] = {};
#pragma unroll
  for (int s = 0; s < NSPLIT; ++s) {
    float ws = __builtin_amdgcn_exp2f(mpart[s * NSP + q] - M);
    L += ws * lpart[s * NSP + q];
    bf16x8 o = *(const bf16x8*)(Opart + ((size_t)s * NSP + q) * 256 + c8 * 8);
#pragma unroll
    for (int j = 0; j < 8; ++j) av[j] += ws * bf2f((ushort)o[j]);
  }
  float rL = 1.f / L;
  uint4 outv;
  outv.x = pk2bf(av[0] * rL, av[1] * rL);
  outv.y = pk2bf(av[2] * rL, av[3] * rL);
  outv.z = pk2bf(av[4] * rL, av[5] * rL);
  outv.w = pk2bf(av[6] * rL, av[7] * rL);
  *(uint4*)(attT + (size_t)q * 256 + c8 * 8) = outv;
}

// ---------------- K7: out = xn + ow @ att + ob ------------------------------
__global__ __launch_bounds__(256) void k_final(const ushort* __restrict__ attT, const ushort* __restrict__ wo,
                                               const float* __restrict__ ob, const float* __restrict__ x,
                                               const float* __restrict__ gw, const float* __restrict__ gb,
                                               const float* __restrict__ stat, float* __restrict__ out) {
  int nb = blockIdx.x, obk = blockIdx.y;
  int w = threadIdx.x >> 6, lane = threadIdx.x & 63;
  int l16 = lane & 15, kgrp = lane >> 4;
  int orow = obk * 64 + w * 16 + l16;
  bf16x8 a[8];
  const bf16x8* arow = (const bf16x8*)(wo + (size_t)orow * 256);
  for (int ks = 0; ks < 8; ++ks) a[ks] = arow[ks * 4 + kgrp];
  float mean = stat[0], rinv = stat[1];
  f32x4 acc[4];
  for (int ct = 0; ct < 4; ++ct) {
    int n = nb * 64 + ct * 16 + l16;
    const bf16x8* brow = (const bf16x8*)(attT + (size_t)n * 256);
    f32x4 c = {0.f, 0.f, 0.f, 0.f};
    for (int ks = 0; ks < 8; ++ks)
      c = __builtin_amdgcn_mfma_f32_16x16x32_bf16(a[ks], brow[ks * 4 + kgrp], c, 0, 0, 0);
    acc[ct] = c;
  }
  for (int ct = 0; ct < 4; ++ct) {
    for (int r = 0; r < 4; ++r) {
      int o = obk * 64 + w * 16 + kgrp * 4 + r;
      int n = nb * 64 + ct * 16 + l16;
      float xv = x[(size_t)o * NSP + n];
      float xn = (xv - mean) * rinv * gw[o] + gb[o];
      out[(size_t)o * NSP + n] = xn + acc[ct][r] + ob[o];
    }
  }
}

extern "C" void kernel_launch(void* const* d_in, const int* in_sizes, int n_in,
                              void* d_out, int out_size, void* d_ws, size_t ws_size,
                              hipStream_t stream) {
  const float* x = (const float*)d_in[0];
  const float* gw = (const float*)d_in[1];
  const float* gb = (const float*)d_in[2];
  const float* qw = (const float*)d_in[3];
  const float* qbv = (const float*)d_in[4];
  const float* kw = (const float*)d_in[5];
  const float* kbv = (const float*)d_in[6];
  const float* vw = (const float*)d_in[7];
  const float* vbv = (const float*)d_in[8];
  const float* ow = (const float*)d_in[9];
  const float* obv = (const float*)d_in[10];
  float* out = (float*)d_out;
  char* ws = (char*)d_ws;
  const size_t KB = 1024, MB = 1048576;
  // region plan (high-water 49 MB):
  //  0..4K      part
  //  60K        stat
  //  64..448K   wqkv (dead after k_qkv) -> mpart (256K) overlays
  //  448..576K  wo (live until k_final)
  //  576..832K  lpart
  //  1..5MB     xnT (k_norm_t->k_qkv) -> attT (k_combine->k_final)
  //  5..9MB     qT
  //  9..13MB    k_tiles [256 tile][16KB]
  //  13..17MB   v_tiles [256 tile][16KB]
  //  17..49MB   Opart (8 splits, bf16)
  float* part = (float*)(ws);
  float* stat = (float*)(ws + 60 * KB);
  ushort* wqkv = (ushort*)(ws + 64 * KB);
  ushort* wo = (ushort*)(ws + 448 * KB);
  float* mpart = (float*)(ws + 64 * KB);    // overlays wqkv (dead by k_attn)
  float* lpart = (float*)(ws + 576 * KB);
  ushort* xnT = (ushort*)(ws + 1 * MB);
  ushort* qT = (ushort*)(ws + 5 * MB);
  ushort* k_tiles = (ushort*)(ws + 9 * MB);
  ushort* v_tiles = (ushort*)(ws + 13 * MB);
  ushort* Opart = (ushort*)(ws + 17 * MB);
  ushort* attT = xnT;  // alias: xnT dead after k_qkv

  k_stats1<<<512, 256, 0, stream>>>(x, part);
  k_castw<<<1025, 256, 0, stream>>>(qw, kw, vw, ow, wqkv, wo, part, stat);
  k_norm_t<<<dim3(128, 4), 256, 0, stream>>>(x, gw, gb, stat, xnT);
  k_qkv<<<dim3(128, 12), 256, 0, stream>>>(xnT, wqkv, qbv, kbv, vbv, qT, k_tiles, v_tiles);
  k_attn<<<256, 512, 0, stream>>>(qT, k_tiles, v_tiles, Opart, mpart, lpart);
  k_combine<<<NSP / 8, 256, 0, stream>>>(Opart, mpart, lpart, attT);
  k_final<<<dim3(128, 4), 256, 0, stream>>>(attT, wo, obv, x, gw, gb, stat, out);
}